// Round 1
// baseline (110.582 us; speedup 1.0000x reference)
//
#include <hip/hip_runtime.h>
#include <math.h>

// Problem shape (from reference setup_inputs): x = (8, 4096, 2048) f32, AXIS=1
// MX quant-dequant: blocks of 32 along m (the 4096 dim), e4m3 grid, EMAX=8.
#define DIM_B 8
#define DIM_M 4096
#define DIM_N 2048
#define MBLKS (DIM_M / 32)   // 128 blocks along m
#define NPAIR (DIM_N / 2)    // 1024 float2 columns

// Quant-dequant one value given the block's scale / inv_scale (powers of two).
// All ops here are exact in f32 except nothing: mul/div by pow2, rint onto a
// pow2 grid, clip, mul by pow2 are all exact. e = exact floor(log2(|v|)),
// clamped to EMIN=-6 (covers zero/subnormal since exp field 0 -> -127 -> -6).
__device__ __forceinline__ float mx_qd1(float v, float inv_scale, float scale) {
    float vq = v * inv_scale;                       // exact (pow2)
    unsigned ab = __float_as_uint(vq) & 0x7fffffffu;
    int e = (int)(ab >> 23) - 127;                  // exact floor(log2|vq|) for normals
    e = (e < -6) ? -6 : e;                          // EMIN clamp (also fixes 0/subnormal)
    // ulp = 2^(e-3), inv_ulp = 2^(3-e); e in [-6, 128] -> biased exps in [2,252]: safe
    float inv_ulp = __uint_as_float((unsigned)(130 - e) << 23);
    float ulp     = __uint_as_float((unsigned)(e + 124) << 23);
    float q = rintf(vq * inv_ulp) * ulp;            // exact: v/ulp in [-16,16] int grid
    q = fminf(fmaxf(q, -448.0f), 448.0f);           // e4m3 clip
    return q * scale;                               // exact (pow2)
}

__global__ __launch_bounds__(256) void mx_qd_kernel(const float* __restrict__ x,
                                                    float* __restrict__ out) {
    int tid  = blockIdx.x * 256 + threadIdx.x;
    int n2   = tid & (NPAIR - 1);       // float2 column index
    int rest = tid >> 10;               // / NPAIR
    int mblk = rest & (MBLKS - 1);
    int b    = rest >> 7;               // / MBLKS
    size_t base = ((size_t)b * DIM_M + (size_t)mblk * 32) * DIM_N + (size_t)n2 * 2;

    // Load the 32-row block for two adjacent columns; coalesced float2 loads
    // (64 lanes x 8B = 512B contiguous per wave instruction).
    float vx[32], vy[32];
#pragma unroll
    for (int j = 0; j < 32; ++j) {
        float2 t = *reinterpret_cast<const float2*>(x + base + (size_t)j * DIM_N);
        vx[j] = t.x;
        vy[j] = t.y;
    }

    // Per-column block max(|.|)
    float m0 = 0.0f, m1 = 0.0f;
#pragma unroll
    for (int j = 0; j < 32; ++j) {
        m0 = fmaxf(m0, fabsf(vx[j]));
        m1 = fmaxf(m1, fabsf(vy[j]));
    }

    // shared_exp = floor(log2(max_abs)) - 8, via exponent bits (exact floor).
    // scale via exp2f so degenerate tiny maxima behave like the reference;
    // zero block -> scale = inv_scale = 0 -> output zeros (matches where()).
    int  e0 = (int)((__float_as_uint(m0) >> 23) & 0xffu) - 127;
    int  e1 = (int)((__float_as_uint(m1) >> 23) & 0xffu) - 127;
    bool nz0 = (m0 > 0.0f), nz1 = (m1 > 0.0f);
    float s0  = nz0 ? exp2f((float)(e0 - 8)) : 0.0f;
    float is0 = nz0 ? exp2f((float)(8 - e0)) : 0.0f;
    float s1  = nz1 ? exp2f((float)(e1 - 8)) : 0.0f;
    float is1 = nz1 ? exp2f((float)(8 - e1)) : 0.0f;

    // Quantize-dequantize from registers and store (coalesced float2).
#pragma unroll
    for (int j = 0; j < 32; ++j) {
        float2 o;
        o.x = mx_qd1(vx[j], is0, s0);
        o.y = mx_qd1(vy[j], is1, s1);
        *reinterpret_cast<float2*>(out + base + (size_t)j * DIM_N) = o;
    }
}

extern "C" void kernel_launch(void* const* d_in, const int* in_sizes, int n_in,
                              void* d_out, int out_size, void* d_ws, size_t ws_size,
                              hipStream_t stream) {
    const float* x = (const float*)d_in[0];
    float* out = (float*)d_out;
    (void)in_sizes; (void)n_in; (void)out_size; (void)d_ws; (void)ws_size;
    const int total_threads = DIM_B * MBLKS * NPAIR;  // 1,048,576
    const int block = 256;
    const int grid = total_threads / block;           // 4096 blocks
    mx_qd_kernel<<<grid, block, 0, stream>>>(x, out);
}

// Round 2
// 87.469 us; speedup vs baseline: 1.2642x; 1.2642x over previous
//
#include <hip/hip_runtime.h>
#include <math.h>

// x = (8, 4096, 2048) f32; MX quant-dequant with BLOCK=32 along m (the 4096 dim).
// e4m3 grid: EMAX=8, MBITS=3, EMIN=-6, clip +-448.
#define DIM_B 8
#define DIM_M 4096
#define DIM_N 2048
#define MBLKS (DIM_M / 32)   // 128
#define N4G   (DIM_N / 4 / 64) // 8 groups of 64 float4-columns

typedef float f4 __attribute__((ext_vector_type(4)));

// Quant-dequant one value given the block's pow2 scale / inv_scale.
// mul/div by pow2, rint onto pow2 grid, clip, mul by pow2 are all exact in f32.
// e = exact floor(log2(|vq|)) from exponent bits, clamped to EMIN=-6
// (exp field 0 -> -127 -> clamps to -6, covering zero/subnormal).
__device__ __forceinline__ float mx_qd1(float v, float inv_scale, float scale) {
    float vq = v * inv_scale;                       // exact (pow2)
    unsigned ab = __float_as_uint(vq) & 0x7fffffffu;
    int e = (int)(ab >> 23) - 127;
    e = (e < -6) ? -6 : e;
    // ulp = 2^(e-3), inv_ulp = 2^(3-e); biased exponents stay in [2,252]: safe
    float inv_ulp = __uint_as_float((unsigned)(130 - e) << 23);
    float ulp     = __uint_as_float((unsigned)(e + 124) << 23);
    float q = rintf(vq * inv_ulp) * ulp;            // exact grid snap
    q = fminf(fmaxf(q, -448.0f), 448.0f);           // e4m3 clip
    return q * scale;                               // exact (pow2)
}

// Block = 256 threads = 64 lanes (float4 columns) x 4 m-subgroups (8 rows each).
// Each thread: load 8 x float4 (16B/lane, 1KiB per wave instr), partial |max|,
// 4KB LDS reduce across the 4 subgroups, then quantize+store from registers.
__global__ __launch_bounds__(256) void mx_qd_kernel(const float* __restrict__ x,
                                                    float* __restrict__ out) {
    __shared__ f4 red[4][64];
    const int lane = threadIdx.x & 63;
    const int mg   = threadIdx.x >> 6;   // wave index == m-subgroup (wave-uniform)
    const int wg   = blockIdx.x;
    const int n4g  = wg & (N4G - 1);
    const int rest = wg >> 3;
    const int mblk = rest & (MBLKS - 1);
    const int b    = rest >> 7;
    const size_t base = ((size_t)b * DIM_M + (size_t)mblk * 32 + (size_t)mg * 8) * DIM_N
                      + ((size_t)(n4g * 64 + lane)) * 4;

    f4 v[8];
#pragma unroll
    for (int j = 0; j < 8; ++j)
        v[j] = __builtin_nontemporal_load(reinterpret_cast<const f4*>(x + base + (size_t)j * DIM_N));

    // Per-column partial max over this thread's 8 rows.
    f4 pm = {0.0f, 0.0f, 0.0f, 0.0f};
#pragma unroll
    for (int j = 0; j < 8; ++j) {
#pragma unroll
        for (int k = 0; k < 4; ++k)
            pm[k] = fmaxf(pm[k], fabsf(v[j][k]));
    }

    red[mg][lane] = pm;
    __syncthreads();

    const f4 r0 = red[0][lane], r1 = red[1][lane], r2 = red[2][lane], r3 = red[3][lane];
    f4 mx;
#pragma unroll
    for (int k = 0; k < 4; ++k)
        mx[k] = fmaxf(fmaxf(r0[k], r1[k]), fmaxf(r2[k], r3[k]));

    // shared_exp = floor(log2(max_abs)) - 8 via exponent bits (exact floor);
    // zero block -> scale = inv_scale = 0 -> zeros out, matching the reference.
    f4 sc, isc;
#pragma unroll
    for (int k = 0; k < 4; ++k) {
        int  e  = (int)((__float_as_uint(mx[k]) >> 23) & 0xffu) - 127;
        bool nz = (mx[k] > 0.0f);
        sc[k]  = nz ? exp2f((float)(e - 8)) : 0.0f;
        isc[k] = nz ? exp2f((float)(8 - e)) : 0.0f;
    }

#pragma unroll
    for (int j = 0; j < 8; ++j) {
        f4 o;
#pragma unroll
        for (int k = 0; k < 4; ++k)
            o[k] = mx_qd1(v[j][k], isc[k], sc[k]);
        __builtin_nontemporal_store(o, reinterpret_cast<f4*>(out + base + (size_t)j * DIM_N));
    }
}

extern "C" void kernel_launch(void* const* d_in, const int* in_sizes, int n_in,
                              void* d_out, int out_size, void* d_ws, size_t ws_size,
                              hipStream_t stream) {
    const float* x = (const float*)d_in[0];
    float* out = (float*)d_out;
    (void)in_sizes; (void)n_in; (void)out_size; (void)d_ws; (void)ws_size;
    const int grid = DIM_B * MBLKS * N4G;  // 8 * 128 * 8 = 8192 workgroups
    mx_qd_kernel<<<grid, 256, 0, stream>>>(x, out);
}